// Round 3
// baseline (92.443 us; speedup 1.0000x reference)
//
#include <hip/hip_runtime.h>

#define NN 256
#define HH 512
#define BB 128
#define PKS (5 * HH)   // floats per packed step row-set (w2m, w2a, w0, w1a, w1b)

// ---------------- prep: packed masked/transposed rows, one row-set per step -
// pk[i][0][k] = (k%255 <  i)        ? w2[i][k]       (mu row)
// pk[i][1][k] = (k%255 <  i)        ? w2[256+i][k]   (alpha row)
// pk[i][2][k] = (k%255 >= i)        ? w0[k][i]       (w0 column i)
// pk[i][3][k] = (k%255 >= i%255)    ? w1[k][i]       (w1 column i)
// pk[i][4][k] = (k%255 >= (i+255)%255) ? w1[k][i+255]
__global__ __launch_bounds__(512)
void made_prep(const float* __restrict__ w0,
               const float* __restrict__ w1,
               const float* __restrict__ w2,
               float* __restrict__ pk) {
    const int i = blockIdx.x;     // step 0..255
    const int k = threadIdx.x;    // unit 0..511
    const int lev = k % 255;
    float* row = pk + (size_t)i * PKS;
    row[k]          = (lev < i)  ? w2[i * HH + k]        : 0.f;
    row[HH + k]     = (lev < i)  ? w2[(NN + i) * HH + k] : 0.f;
    row[2*HH + k]   = (lev >= i) ? w0[k * NN + i]        : 0.f;
    const int l1 = i % 255;
    row[3*HH + k]   = (lev >= l1) ? w1[k * HH + i]       : 0.f;
    const int j2 = i + 255;
    const int l2 = j2 % 255;
    row[4*HH + k]   = (lev >= l2) ? w1[k * HH + j2]      : 0.f;
}

// ---------------- single-wave sequential kernel -----------------------------
struct B10 { float4 q0,q1,q2,q3,q4,q5,q6,q7,q8,q9; };

__device__ __forceinline__ float4 ld4(const float* p) { return *(const float4*)p; }

__device__ __forceinline__ void load_all(B10& b, const float* p, int o8) {
    b.q0 = ld4(p + o8);          b.q1 = ld4(p + o8 + 4);
    b.q2 = ld4(p + HH + o8);     b.q3 = ld4(p + HH + o8 + 4);
    b.q4 = ld4(p + 2*HH + o8);   b.q5 = ld4(p + 2*HH + o8 + 4);
    b.q6 = ld4(p + 3*HH + o8);   b.q7 = ld4(p + 3*HH + o8 + 4);
    b.q8 = ld4(p + 4*HH + o8);   b.q9 = ld4(p + 4*HH + o8 + 4);
}

__device__ __forceinline__ float rl_f(float v, int lane) {
    return __int_as_float(__builtin_amdgcn_readlane(__float_as_int(v), lane));
}

// pick element s (compile-time) of the 8 w0 values held in q4/q5
__device__ __forceinline__ float q45c(const B10& b, int s) {
    switch (s) {
        case 0: return b.q4.x; case 1: return b.q4.y;
        case 2: return b.q4.z; case 3: return b.q4.w;
        case 4: return b.q5.x; case 5: return b.q5.y;
        case 6: return b.q5.z; default: return b.q5.w;
    }
}

#define DPP_ADD(v, ctrl, rm) \
    ((v) + __int_as_float(__builtin_amdgcn_update_dpp(0, __float_as_int(v), (ctrl), (rm), 0xf, false)))

// full-wave (64-lane) sum of pm and pa; totals end up in lane 63
__device__ __forceinline__ void reduce2(float& pm, float& pa) {
    pm = DPP_ADD(pm, 0x111, 0xf);  pa = DPP_ADD(pa, 0x111, 0xf);  // row_shr:1
    pm = DPP_ADD(pm, 0x112, 0xf);  pa = DPP_ADD(pa, 0x112, 0xf);  // row_shr:2
    pm = DPP_ADD(pm, 0x114, 0xf);  pa = DPP_ADD(pa, 0x114, 0xf);  // row_shr:4
    pm = DPP_ADD(pm, 0x118, 0xf);  pa = DPP_ADD(pa, 0x118, 0xf);  // row_shr:8
    pm = DPP_ADD(pm, 0x142, 0xa);  pa = DPP_ADD(pa, 0x142, 0xa);  // row_bcast15
    pm = DPP_ADD(pm, 0x143, 0xc);  pa = DPP_ADD(pa, 0x143, 0xc);  // row_bcast31
}

#define DOT8(res, A, B)  do {                                   \
    float t01_ = fmaf(h_[1], (A).y, h_[0] * (A).x);             \
    float t23_ = fmaf(h_[3], (A).w, h_[2] * (A).z);             \
    float t45_ = fmaf(h_[5], (B).y, h_[4] * (B).x);             \
    float t67_ = fmaf(h_[7], (B).w, h_[6] * (B).z);             \
    res = (t01_ + t23_) + (t45_ + t67_);                        \
} while (0)

// One autoregressive step. r is a literal 0..7; BUF is the parity buffer
// holding step i's rows; its quarters are refilled for step i+2 right after
// their last read (distance-2 software pipeline).
#define STEP(g, r, BUF) do {                                                 \
    const int i_  = ((g) << 3) | (r);                                        \
    const float* pf_ = pk + (size_t)((i_ + 2) & 255) * PKS;                  \
    float h_[8];                                                             \
    h_[0] = fmaxf(a1v[0], 0.f); h_[1] = fmaxf(a1v[1], 0.f);                  \
    h_[2] = fmaxf(a1v[2], 0.f); h_[3] = fmaxf(a1v[3], 0.f);                  \
    h_[4] = fmaxf(a1v[4], 0.f); h_[5] = fmaxf(a1v[5], 0.f);                  \
    h_[6] = fmaxf(a1v[6], 0.f); h_[7] = fmaxf(a1v[7], 0.f);                  \
    float pm_, pa_;                                                          \
    DOT8(pm_, BUF.q0, BUF.q1);                                               \
    DOT8(pa_, BUF.q2, BUF.q3);                                               \
    BUF.q0 = ld4(pf_ + o8);        BUF.q1 = ld4(pf_ + o8 + 4);               \
    BUF.q2 = ld4(pf_ + HH + o8);   BUF.q3 = ld4(pf_ + HH + o8 + 4);          \
    reduce2(pm_, pa_);                                                       \
    const int sB_ = ((r) + 7) & 7;                                           \
    const int LB_ = ((r) == 0) ? ((g) + 31) : ((g) + 32);                    \
    const int zl_ = ((g) << 1) + ((r) >> 2);                                 \
    float a0A_ = rl_f(a0v[(r)], (g));                                        \
    float w0A_ = rl_f(q45c(BUF, (r)), (g));                                  \
    float a0B_ = rl_f(a0v[sB_], LB_);                                        \
    float w0B_ = rl_f(q45c(BUF, sB_), LB_);                                  \
    float tm_ = rl_f(pm_, 63), ta_ = rl_f(pa_, 63);                          \
    float mu_ = tm_ + rl_f(b2v[(r)], (g));                                   \
    float al_ = ta_ + rl_f(b2v[(r)], (g) + 32);                              \
    ldacc += al_;                                                            \
    float zi_ = rl_f(zrv[(r) & 3], zl_);                                     \
    float xi_ = fmaf(zi_, __expf(al_), mu_);                                 \
    xo[(r) & 3] = (t == zl_) ? xi_ : xo[(r) & 3];                            \
    float h0a_ = fmaxf(fmaf(xi_, w0A_, a0A_), 0.f);                          \
    float h0b_ = fmaxf(fmaf(xi_, w0B_, a0B_), 0.f);                          \
    if ((r) < 2 && (g) == 0) {  /* units 510/511 finalize at i=0,1 */        \
        float a0C_ = rl_f(a0v[6 + (r)], 63);                                 \
        float w0C_ = rl_f(q45c(BUF, 6 + (r)), 63);                           \
        float h0c_ = fmaxf(fmaf(xi_, w0C_, a0C_), 0.f);                      \
        const float* wc_ = ((r) == 0) ? w1c0v : w1c1v;                       \
        a1v[0] = fmaf(h0c_, wc_[0], a1v[0]); a1v[1] = fmaf(h0c_, wc_[1], a1v[1]); \
        a1v[2] = fmaf(h0c_, wc_[2], a1v[2]); a1v[3] = fmaf(h0c_, wc_[3], a1v[3]); \
        a1v[4] = fmaf(h0c_, wc_[4], a1v[4]); a1v[5] = fmaf(h0c_, wc_[5], a1v[5]); \
        a1v[6] = fmaf(h0c_, wc_[6], a1v[6]); a1v[7] = fmaf(h0c_, wc_[7], a1v[7]); \
    }                                                                        \
    a0v[0] = fmaf(xi_, BUF.q4.x, a0v[0]); a0v[1] = fmaf(xi_, BUF.q4.y, a0v[1]); \
    a0v[2] = fmaf(xi_, BUF.q4.z, a0v[2]); a0v[3] = fmaf(xi_, BUF.q4.w, a0v[3]); \
    a0v[4] = fmaf(xi_, BUF.q5.x, a0v[4]); a0v[5] = fmaf(xi_, BUF.q5.y, a0v[5]); \
    a0v[6] = fmaf(xi_, BUF.q5.z, a0v[6]); a0v[7] = fmaf(xi_, BUF.q5.w, a0v[7]); \
    BUF.q4 = ld4(pf_ + 2*HH + o8); BUF.q5 = ld4(pf_ + 2*HH + o8 + 4);        \
    a1v[0] = fmaf(h0b_, BUF.q8.x, fmaf(h0a_, BUF.q6.x, a1v[0]));             \
    a1v[1] = fmaf(h0b_, BUF.q8.y, fmaf(h0a_, BUF.q6.y, a1v[1]));             \
    a1v[2] = fmaf(h0b_, BUF.q8.z, fmaf(h0a_, BUF.q6.z, a1v[2]));             \
    a1v[3] = fmaf(h0b_, BUF.q8.w, fmaf(h0a_, BUF.q6.w, a1v[3]));             \
    a1v[4] = fmaf(h0b_, BUF.q9.x, fmaf(h0a_, BUF.q7.x, a1v[4]));             \
    a1v[5] = fmaf(h0b_, BUF.q9.y, fmaf(h0a_, BUF.q7.y, a1v[5]));             \
    a1v[6] = fmaf(h0b_, BUF.q9.z, fmaf(h0a_, BUF.q7.z, a1v[6]));             \
    a1v[7] = fmaf(h0b_, BUF.q9.w, fmaf(h0a_, BUF.q7.w, a1v[7]));             \
    BUF.q6 = ld4(pf_ + 3*HH + o8); BUF.q7 = ld4(pf_ + 3*HH + o8 + 4);        \
    BUF.q8 = ld4(pf_ + 4*HH + o8); BUF.q9 = ld4(pf_ + 4*HH + o8 + 4);        \
} while (0)

// One 64-thread wave per batch element. Lane t owns units 8t..8t+7.
// min-waves-per-EU = 1: allow the allocator ~500 VGPRs so both pipeline
// buffers (80 VGPRs) stay live — this is the whole point of this version.
__global__ __launch_bounds__(64, 1)
void made_seq64(const float* __restrict__ z,
                const float* __restrict__ b0g,
                const float* __restrict__ b1g,
                const float* __restrict__ b2g,
                const float* __restrict__ w1,
                const float* __restrict__ pk,
                float* __restrict__ out) {
    const int bb = blockIdx.x;
    const int t  = threadIdx.x;
    const int o8 = t << 3;

    float a0v[8], a1v[8], b2v[8];
    {
        float4 a = ld4(b0g + o8), b = ld4(b0g + o8 + 4);
        a0v[0]=a.x; a0v[1]=a.y; a0v[2]=a.z; a0v[3]=a.w;
        a0v[4]=b.x; a0v[5]=b.y; a0v[6]=b.z; a0v[7]=b.w;
        a = ld4(b1g + o8); b = ld4(b1g + o8 + 4);
        a1v[0]=a.x; a1v[1]=a.y; a1v[2]=a.z; a1v[3]=a.w;
        a1v[4]=b.x; a1v[5]=b.y; a1v[6]=b.z; a1v[7]=b.w;
        a = ld4(b2g + o8); b = ld4(b2g + o8 + 4);
        b2v[0]=a.x; b2v[1]=a.y; b2v[2]=a.z; b2v[3]=a.w;
        b2v[4]=b.x; b2v[5]=b.y; b2v[6]=b.z; b2v[7]=b.w;
    }
    float w1c0v[8], w1c1v[8];           // w1t rows 510, 511 (one-time gather)
    #pragma unroll
    for (int j = 0; j < 8; ++j) {
        const int k = o8 + j;
        w1c0v[j] = w1[k * HH + 510];
        w1c1v[j] = ((k % 255) >= 1) ? w1[k * HH + 511] : 0.f;
    }
    float4 z4 = ld4(z + (bb << 8) + (t << 2));
    float zrv[4] = {z4.x, z4.y, z4.z, z4.w};
    float xo[4]  = {0.f, 0.f, 0.f, 0.f};
    float ldacc  = 0.f;

    B10 Ba, Bb;                         // even steps in Ba, odd in Bb
    load_all(Ba, pk, o8);
    load_all(Bb, pk + PKS, o8);

    for (int g = 0; g < 32; ++g) {
        STEP(g, 0, Ba); STEP(g, 1, Bb); STEP(g, 2, Ba); STEP(g, 3, Bb);
        STEP(g, 4, Ba); STEP(g, 5, Bb); STEP(g, 6, Ba); STEP(g, 7, Bb);
    }

    *(float4*)(out + (bb << 8) + (t << 2)) = make_float4(xo[0], xo[1], xo[2], xo[3]);
    if (t == 0) out[BB * NN + bb] = -ldacc;
}

// ---------------- fallback (no workspace): verified round-1 kernel ----------
__global__ __launch_bounds__(256)
void made_seq_fb(const float* __restrict__ z,
                 const float* __restrict__ w0, const float* __restrict__ b0,
                 const float* __restrict__ w1, const float* __restrict__ b1,
                 const float* __restrict__ w2, const float* __restrict__ b2,
                 float* __restrict__ out) {
    const int bb = blockIdx.x;
    const int t  = threadIdx.x;
    const int u0 = t, u1 = t + 256;
    const int l0 = u0 % 255, s0 = u0 / 255;
    const int l1 = u1 % 255, s1 = u1 / 255;
    const int wave = t >> 6, lane = t & 63;

    __shared__ float red[2][4][2];
    __shared__ float pub[2][3][2];

    float a0_0 = b0[u0], a0_1 = b0[u1];
    float a1_0 = b1[u0], a1_1 = b1[u1];
    float ld = 0.f;

    for (int i = 0; i < NN; ++i) {
        float cw2m0 = (l0 < i) ? w2[i * HH + u0] : 0.f;
        float cw2a0 = (l0 < i) ? w2[(NN + i) * HH + u0] : 0.f;
        float cw2m1 = (l1 < i) ? w2[i * HH + u1] : 0.f;
        float cw2a1 = (l1 < i) ? w2[(NN + i) * HH + u1] : 0.f;
        float cw00  = (l0 >= i) ? w0[u0 * NN + i] : 0.f;
        float cw01  = (l1 >= i) ? w0[u1 * NN + i] : 0.f;
        bool g0 = (l0 >= (i % 255)), g1 = (l1 >= (i % 255));
        float w1a0 = g0 ? w1[u0 * HH + i] : 0.f;
        float w1a1 = g1 ? w1[u1 * HH + i] : 0.f;
        float w1b0 = g0 ? w1[u0 * HH + i + 255] : 0.f;
        float w1b1 = g1 ? w1[u1 * HH + i + 255] : 0.f;

        float h10 = fmaxf(a1_0, 0.f), h11 = fmaxf(a1_1, 0.f);
        float pm = h10 * cw2m0 + h11 * cw2m1;
        float pa = h10 * cw2a0 + h11 * cw2a1;
        #pragma unroll
        for (int offs = 32; offs > 0; offs >>= 1) {
            pm += __shfl_xor(pm, offs);
            pa += __shfl_xor(pa, offs);
        }
        const int bf = i & 1;
        if (lane == 0) { red[bf][wave][0] = pm; red[bf][wave][1] = pa; }
        if (l0 == i) { pub[bf][s0][0] = a0_0; pub[bf][s0][1] = cw00; }
        if (l1 == i) { pub[bf][s1][0] = a0_1; pub[bf][s1][1] = cw01; }
        __syncthreads();

        float mu = b2[i]      + red[bf][0][0] + red[bf][1][0] + red[bf][2][0] + red[bf][3][0];
        float al = b2[NN + i] + red[bf][0][1] + red[bf][1][1] + red[bf][2][1] + red[bf][3][1];
        ld += al;
        float xi = fmaf(z[bb * NN + i], __expf(al), mu);
        if (t == 0) out[bb * NN + i] = xi;

        a0_0 = fmaf(xi, cw00, a0_0);
        a0_1 = fmaf(xi, cw01, a0_1);

        float h0a = fmaxf(fmaf(xi, pub[bf][0][1], pub[bf][0][0]), 0.f);
        float h0b = fmaxf(fmaf(xi, pub[bf][1][1], pub[bf][1][0]), 0.f);
        a1_0 = fmaf(h0a, w1a0, a1_0);
        a1_1 = fmaf(h0a, w1a1, a1_1);
        a1_0 = fmaf(h0b, w1b0, a1_0);
        a1_1 = fmaf(h0b, w1b1, a1_1);
        if (i < 2) {
            float w1c0 = (l0 >= i) ? w1[u0 * HH + i + 510] : 0.f;
            float w1c1 = (l1 >= i) ? w1[u1 * HH + i + 510] : 0.f;
            float h0c = fmaxf(fmaf(xi, pub[bf][2][1], pub[bf][2][0]), 0.f);
            a1_0 = fmaf(h0c, w1c0, a1_0);
            a1_1 = fmaf(h0c, w1c1, a1_1);
        }
        __syncthreads();
    }

    if (t == 0) out[BB * NN + bb] = -ld;
}

extern "C" void kernel_launch(void* const* d_in, const int* in_sizes, int n_in,
                              void* d_out, int out_size, void* d_ws, size_t ws_size,
                              hipStream_t stream) {
    const float* z  = (const float*)d_in[0];
    const float* w0 = (const float*)d_in[1];
    const float* b0 = (const float*)d_in[2];
    const float* w1 = (const float*)d_in[3];
    const float* b1 = (const float*)d_in[4];
    const float* w2 = (const float*)d_in[5];
    const float* b2 = (const float*)d_in[6];
    float* out = (float*)d_out;

    const size_t need = (size_t)NN * PKS * sizeof(float);   // 2,621,440 B (same as before)
    if (ws_size >= need) {
        float* pk = (float*)d_ws;
        made_prep<<<NN, 512, 0, stream>>>(w0, w1, w2, pk);
        made_seq64<<<BB, 64, 0, stream>>>(z, b0, b1, b2, w1, pk, out);
    } else {
        made_seq_fb<<<BB, 256, 0, stream>>>(z, w0, b0, w1, b1, w2, b2, out);
    }
}